// Round 1
// baseline (8130.009 us; speedup 1.0000x reference)
//
#include <hip/hip_runtime.h>

// Problem constants (reference: T=64 time steps, B=SEQ=128 batch, IN=256, H=512)
#define TT 64
#define BB 128
#define IND 256
#define HH 512
#define GG 2048      // 4*H
#define NCC 10
#define KFLAT 65536  // SEQ*H

// ---------------------------------------------------------------------------
// GEMM: C[m,n] = sum_k A[m,k]*W[n,k] + b0[n] + b1[n]
// A: [M,K] row-major, W: [N,K] row-major. 64x64 tile, Kt=32, 256 thr, 4x4 micro.
// ---------------------------------------------------------------------------
__global__ __launch_bounds__(256) void gemm_bias_kernel(
    const float* __restrict__ A, const float* __restrict__ W,
    const float* __restrict__ b0, const float* __restrict__ b1,
    float* __restrict__ C, int K, int N)
{
    const int m0 = blockIdx.x * 64;
    const int n0 = blockIdx.y * 64;
    const int tid = threadIdx.x;
    __shared__ float As[32][68];   // k-major, padded: rows 16B-aligned, bank-staggered
    __shared__ float Bs[32][68];
    const int tm = tid >> 4;   // 0..15
    const int tn = tid & 15;   // 0..15
    float acc[4][4] = {};

    for (int kt = 0; kt < K; kt += 32) {
        #pragma unroll
        for (int q = tid; q < 512; q += 256) {
            const int mm = q >> 3;      // 0..63
            const int kq = q & 7;       // 0..7
            float4 v = *(const float4*)&A[(size_t)(m0 + mm) * K + kt + kq * 4];
            As[kq*4+0][mm] = v.x; As[kq*4+1][mm] = v.y;
            As[kq*4+2][mm] = v.z; As[kq*4+3][mm] = v.w;
            float4 w = *(const float4*)&W[(size_t)(n0 + mm) * K + kt + kq * 4];
            Bs[kq*4+0][mm] = w.x; Bs[kq*4+1][mm] = w.y;
            Bs[kq*4+2][mm] = w.z; Bs[kq*4+3][mm] = w.w;
        }
        __syncthreads();
        #pragma unroll
        for (int k = 0; k < 32; ++k) {
            float4 a = *(const float4*)&As[k][tm * 4];
            float4 b = *(const float4*)&Bs[k][tn * 4];
            acc[0][0] += a.x*b.x; acc[0][1] += a.x*b.y; acc[0][2] += a.x*b.z; acc[0][3] += a.x*b.w;
            acc[1][0] += a.y*b.x; acc[1][1] += a.y*b.y; acc[1][2] += a.y*b.z; acc[1][3] += a.y*b.w;
            acc[2][0] += a.z*b.x; acc[2][1] += a.z*b.y; acc[2][2] += a.z*b.z; acc[2][3] += a.z*b.w;
            acc[3][0] += a.w*b.x; acc[3][1] += a.w*b.y; acc[3][2] += a.w*b.z; acc[3][3] += a.w*b.w;
        }
        __syncthreads();
    }
    #pragma unroll
    for (int i = 0; i < 4; ++i) {
        const int m = m0 + tm * 4 + i;
        #pragma unroll
        for (int j = 0; j < 4; ++j) {
            const int n = n0 + tn * 4 + j;
            C[(size_t)m * N + n] = acc[i][j] + b0[n] + b1[n];
        }
    }
}

// ---------------------------------------------------------------------------
// One LSTM time step, fused: gates = xg_t + h_prev @ W_hh^T; c,h update.
// Grid (B/16, H/16) = (8,32); 256 threads; one (b, j) cell per thread.
// h_prev tile staged in LDS; W_hh rows read from global (L1/L2 resident).
// ---------------------------------------------------------------------------
__global__ __launch_bounds__(256) void lstm_step_kernel(
    const float* __restrict__ xg,      // [B, 4H] for this t
    const float* __restrict__ h_prev,  // [B, H] or nullptr (t==0)
    const float* __restrict__ w_hh,    // [4H, H]
    float* __restrict__ c,             // [B, H] in/out
    float* __restrict__ h_out)         // [B, H]
{
    const int tid = threadIdx.x;
    const int bl  = tid >> 4;                 // 0..15 local batch
    const int j   = tid & 15;                 // 0..15 local hidden
    const int b   = blockIdx.x * 16 + bl;
    const int jg  = blockIdx.y * 16 + j;

    __shared__ float Hs[16][516];             // padded: rows 16B-aligned, bank-staggered

    float a0 = 0.f, a1 = 0.f, a2 = 0.f, a3 = 0.f;
    if (h_prev) {
        const int row = tid >> 4, cc = tid & 15;
        const float* src = h_prev + (size_t)(blockIdx.x * 16 + row) * HH;
        #pragma unroll
        for (int i = 0; i < 8; ++i) {
            const int c4 = cc + i * 16;
            *(float4*)&Hs[row][c4 * 4] = *(const float4*)&src[c4 * 4];
        }
        __syncthreads();

        const float* wr0 = w_hh + (size_t)(0 * HH + jg) * HH;
        const float* wr1 = w_hh + (size_t)(1 * HH + jg) * HH;
        const float* wr2 = w_hh + (size_t)(2 * HH + jg) * HH;
        const float* wr3 = w_hh + (size_t)(3 * HH + jg) * HH;
        #pragma unroll 4
        for (int k4 = 0; k4 < HH / 4; ++k4) {
            float4 h  = *(const float4*)&Hs[bl][k4 * 4];
            float4 w0 = *(const float4*)&wr0[k4 * 4];
            float4 w1 = *(const float4*)&wr1[k4 * 4];
            float4 w2 = *(const float4*)&wr2[k4 * 4];
            float4 w3 = *(const float4*)&wr3[k4 * 4];
            a0 += h.x*w0.x + h.y*w0.y + h.z*w0.z + h.w*w0.w;
            a1 += h.x*w1.x + h.y*w1.y + h.z*w1.z + h.w*w1.w;
            a2 += h.x*w2.x + h.y*w2.y + h.z*w2.z + h.w*w2.w;
            a3 += h.x*w3.x + h.y*w3.y + h.z*w3.z + h.w*w3.w;
        }
    }

    const size_t xb = (size_t)b * GG + jg;
    const float gi = xg[xb]            + a0;
    const float gf = xg[xb + HH]       + a1;
    const float gg = xg[xb + 2 * HH]   + a2;
    const float go = xg[xb + 3 * HH]   + a3;

    const float si = 1.f / (1.f + __expf(-gi));
    const float sf = 1.f / (1.f + __expf(-gf));
    const float tg = 2.f / (1.f + __expf(-2.f * gg)) - 1.f;
    const float so = 1.f / (1.f + __expf(-go));

    const size_t ci = (size_t)b * HH + jg;
    const float cv = c[ci];
    const float cn = sf * cv + si * tg;
    const float th = 2.f / (1.f + __expf(-2.f * cn)) - 1.f;
    c[ci] = cn;
    h_out[ci] = so * th;
}

// ---------------------------------------------------------------------------
// Classifier split-K partial GEMM: part[s][t][n] = sum_{k in slice s} A[t,k]*W[n,k]
// A: [64, 65536] (h1 flat), W: [512, 65536]. Grid (512/64, 32 slices).
// ---------------------------------------------------------------------------
__global__ __launch_bounds__(256) void cls_partial_kernel(
    const float* __restrict__ A, const float* __restrict__ W,
    float* __restrict__ part)
{
    const int n0 = blockIdx.x * 64;
    const int s  = blockIdx.y;
    const int kbase = s * 2048;
    const int tid = threadIdx.x;
    __shared__ float As[32][68];
    __shared__ float Bs[32][68];
    const int tm = tid >> 4, tn = tid & 15;
    float acc[4][4] = {};

    for (int kt = 0; kt < 2048; kt += 32) {
        #pragma unroll
        for (int q = tid; q < 512; q += 256) {
            const int mm = q >> 3;
            const int kq = q & 7;
            float4 v = *(const float4*)&A[(size_t)mm * KFLAT + kbase + kt + kq * 4];
            As[kq*4+0][mm] = v.x; As[kq*4+1][mm] = v.y;
            As[kq*4+2][mm] = v.z; As[kq*4+3][mm] = v.w;
            float4 w = *(const float4*)&W[(size_t)(n0 + mm) * KFLAT + kbase + kt + kq * 4];
            Bs[kq*4+0][mm] = w.x; Bs[kq*4+1][mm] = w.y;
            Bs[kq*4+2][mm] = w.z; Bs[kq*4+3][mm] = w.w;
        }
        __syncthreads();
        #pragma unroll
        for (int k = 0; k < 32; ++k) {
            float4 a = *(const float4*)&As[k][tm * 4];
            float4 b = *(const float4*)&Bs[k][tn * 4];
            acc[0][0] += a.x*b.x; acc[0][1] += a.x*b.y; acc[0][2] += a.x*b.z; acc[0][3] += a.x*b.w;
            acc[1][0] += a.y*b.x; acc[1][1] += a.y*b.y; acc[1][2] += a.y*b.z; acc[1][3] += a.y*b.w;
            acc[2][0] += a.z*b.x; acc[2][1] += a.z*b.y; acc[2][2] += a.z*b.z; acc[2][3] += a.z*b.w;
            acc[3][0] += a.w*b.x; acc[3][1] += a.w*b.y; acc[3][2] += a.w*b.z; acc[3][3] += a.w*b.w;
        }
        __syncthreads();
    }
    #pragma unroll
    for (int i = 0; i < 4; ++i) {
        const int m = tm * 4 + i;  // t index, 0..63
        #pragma unroll
        for (int j = 0; j < 4; ++j) {
            part[((size_t)s * 64 + m) * 512 + n0 + tn * 4 + j] = acc[i][j];
        }
    }
}

// ---------------------------------------------------------------------------
// Classifier finish: hmid = relu(sum_s part + b1); out = hmid @ w2^T + b2
// Grid 64 (one WG per t).
// ---------------------------------------------------------------------------
__global__ __launch_bounds__(256) void cls_final_kernel(
    const float* __restrict__ part, const float* __restrict__ b1,
    const float* __restrict__ w2, const float* __restrict__ b2,
    float* __restrict__ out)
{
    const int t = blockIdx.x;
    __shared__ float hm[512];
    for (int n = threadIdx.x; n < 512; n += 256) {
        float sacc = b1[n];
        for (int sl = 0; sl < 32; ++sl)
            sacc += part[((size_t)sl * 64 + t) * 512 + n];
        hm[n] = fmaxf(sacc, 0.f);
    }
    __syncthreads();
    if (threadIdx.x < NCC) {
        float sacc = b2[threadIdx.x];
        const float* wr = w2 + (size_t)threadIdx.x * 512;
        for (int n = 0; n < 512; ++n) sacc += hm[n] * wr[n];
        out[t * NCC + threadIdx.x] = sacc;
    }
}

// ---------------------------------------------------------------------------
extern "C" void kernel_launch(void* const* d_in, const int* in_sizes, int n_in,
                              void* d_out, int out_size, void* d_ws, size_t ws_size,
                              hipStream_t stream)
{
    const float* x     = (const float*)d_in[0];
    const float* w_ih0 = (const float*)d_in[1];
    const float* w_hh0 = (const float*)d_in[2];
    const float* b_ih0 = (const float*)d_in[3];
    const float* b_hh0 = (const float*)d_in[4];
    const float* w_ih1 = (const float*)d_in[5];
    const float* w_hh1 = (const float*)d_in[6];
    const float* b_ih1 = (const float*)d_in[7];
    const float* b_hh1 = (const float*)d_in[8];
    const float* w1    = (const float*)d_in[9];
    const float* b1    = (const float*)d_in[10];
    const float* w2    = (const float*)d_in[11];
    const float* b2    = (const float*)d_in[12];
    float* out = (float*)d_out;

    // Workspace layout (floats)
    float* ws   = (float*)d_ws;
    float* xg   = ws;                        // [8192, 2048] = 16,777,216 (reused per layer)
    float* h0   = xg + (size_t)8192 * 2048;  // [8192, 512]  =  4,194,304
    float* h1   = h0 + (size_t)8192 * 512;   // [8192, 512]  =  4,194,304
    float* cbuf = h1 + (size_t)8192 * 512;   // [128, 512]   =     65,536
    float* part = cbuf + (size_t)128 * 512;  // [32][64][512]=  1,048,576

    const size_t strideT_xg = (size_t)BB * GG;  // 262144
    const size_t strideT_h  = (size_t)BB * HH;  // 65536

    // ---- layer 0 ----
    gemm_bias_kernel<<<dim3(8192 / 64, GG / 64), 256, 0, stream>>>(
        x, w_ih0, b_ih0, b_hh0, xg, IND, GG);
    hipMemsetAsync(cbuf, 0, (size_t)BB * HH * sizeof(float), stream);
    for (int t = 0; t < TT; ++t) {
        lstm_step_kernel<<<dim3(BB / 16, HH / 16), 256, 0, stream>>>(
            xg + t * strideT_xg,
            t ? (h0 + (t - 1) * strideT_h) : nullptr,
            w_hh0, cbuf, h0 + t * strideT_h);
    }

    // ---- layer 1 ----
    gemm_bias_kernel<<<dim3(8192 / 64, GG / 64), 256, 0, stream>>>(
        h0, w_ih1, b_ih1, b_hh1, xg, HH, GG);
    hipMemsetAsync(cbuf, 0, (size_t)BB * HH * sizeof(float), stream);
    for (int t = 0; t < TT; ++t) {
        lstm_step_kernel<<<dim3(BB / 16, HH / 16), 256, 0, stream>>>(
            xg + t * strideT_xg,
            t ? (h1 + (t - 1) * strideT_h) : nullptr,
            w_hh1, cbuf, h1 + t * strideT_h);
    }

    // ---- classifier ----
    cls_partial_kernel<<<dim3(512 / 64, 32), 256, 0, stream>>>(h1, w1, part);
    cls_final_kernel<<<64, 256, 0, stream>>>(part, b1, w2, b2, out);
}